// Round 4
// baseline (451.134 us; speedup 1.0000x reference)
//
#include <hip/hip_runtime.h>
#include <stdint.h>

#define IN_F 4096
#define OUT_F 4096
#define NTOK 8192   // 4 * 2048
#define BM 256
#define BN 256
#define BK 64
#define NKT (IN_F / BK)   // 64 K-tiles

typedef int int4v __attribute__((ext_vector_type(4)));

typedef const __attribute__((address_space(1))) void* gas1_t;
typedef __attribute__((address_space(3))) void* gas3_t;

__device__ __forceinline__ void gload_lds16(const int8_t* g, int8_t* l) {
  __builtin_amdgcn_global_load_lds((gas1_t)(const void*)g, (gas3_t)(void*)l, 16, 0, 0);
}

// ---------------------------------------------------------------------------
// Kernel 1: per-token activation quantization (lane-consecutive coalescing).
// ---------------------------------------------------------------------------
__global__ __launch_bounds__(256) void act_quant_kernel(
    const float* __restrict__ x, int8_t* __restrict__ xq, float* __restrict__ xs)
{
  const int row = blockIdx.x;
  const int t = threadIdx.x;
  const float4* xr = reinterpret_cast<const float4*>(x + (size_t)row * IN_F);
  float4 v[4];
  float amax = 0.f;
#pragma unroll
  for (int i = 0; i < 4; ++i) {
    v[i] = xr[t + i * 256];             // lane-consecutive float4: 1KB/wave-instr
    amax = fmaxf(amax, fmaxf(fmaxf(fabsf(v[i].x), fabsf(v[i].y)),
                             fmaxf(fabsf(v[i].z), fabsf(v[i].w))));
  }
#pragma unroll
  for (int off = 32; off; off >>= 1)
    amax = fmaxf(amax, __shfl_xor(amax, off));
  __shared__ float red[4];
  if ((t & 63) == 0) red[t >> 6] = amax;
  __syncthreads();
  amax = fmaxf(fmaxf(red[0], red[1]), fmaxf(red[2], red[3]));
  // IEEE division to match jnp exactly (no -ffast-math)
  const float s = amax / 127.0f;
  if (t == 0) xs[row] = s;

  uint32_t* xqw = reinterpret_cast<uint32_t*>(xq + (size_t)row * IN_F);
#pragma unroll
  for (int i = 0; i < 4; ++i) {
    int q0 = (int)rintf(v[i].x / s);
    int q1 = (int)rintf(v[i].y / s);
    int q2 = (int)rintf(v[i].z / s);
    int q3 = (int)rintf(v[i].w / s);
    q0 = max(-128, min(127, q0));
    q1 = max(-128, min(127, q1));
    q2 = max(-128, min(127, q2));
    q3 = max(-128, min(127, q3));
    xqw[t + i * 256] = (q0 & 255) | ((q1 & 255) << 8) | ((q2 & 255) << 16) | (q3 << 24);
  }
}

// ---------------------------------------------------------------------------
// Kernel 2: weight dequant + transpose to WT[N][K] int8 (verified passing).
// ---------------------------------------------------------------------------
__global__ __launch_bounds__(256) void wdq_kernel(
    const int* __restrict__ qweight, const int* __restrict__ qzeros,
    const float* __restrict__ scales, int8_t* __restrict__ wt)
{
  __shared__ int8_t tile[64 * 144];
  const int t = threadIdx.x;
  const int g = blockIdx.x;
  const int o0 = blockIdx.y * 64;
  const int i0 = g * 16;
  const int ol = t & 63;
  const int o = o0 + ol;

  const int zw = qzeros[g * (OUT_F / 8) + (o >> 3)];
  const int znib = (zw >> ((o & 7) * 4)) & 15;
  const float sc = scales[g * OUT_F + o];

#pragma unroll
  for (int j = 0; j < 4; ++j) {
    const int il = j * 4 + (t >> 6);
    const int w = qweight[(size_t)(i0 + il) * OUT_F + o];
    uint64_t packed = 0;
#pragma unroll
    for (int nb = 0; nb < 8; ++nb) {
      const int wnib = (w >> (nb * 4)) & 15;
      const int8_t diff = (int8_t)(((wnib - znib) & 15) << 4);
      float val = rintf(sc * (float)diff);
      val = fminf(127.f, fmaxf(-128.f, val));
      packed |= (uint64_t)(uint8_t)(int8_t)(int)val << (8 * nb);
    }
    *reinterpret_cast<uint64_t*>(&tile[ol * 144 + il * 8]) = packed;
  }
  __syncthreads();
  const int orow = t >> 2;
  const int kb = (t & 3) * 32;
  int4v w0 = *reinterpret_cast<int4v*>(&tile[orow * 144 + kb]);
  int4v w1 = *reinterpret_cast<int4v*>(&tile[orow * 144 + kb + 16]);
  int8_t* dst = wt + (size_t)(o0 + orow) * IN_F + g * 128 + kb;
  *reinterpret_cast<int4v*>(dst) = w0;
  *reinterpret_cast<int4v*>(dst + 16) = w1;
}

// ---------------------------------------------------------------------------
// Kernel 3: pipelined int8 GEMM. 256x256 tile, BK=64, 8 waves (2Mx4N).
// 4 LDS K-tile buffers (128 KiB dynamic), depth-3 prefetch, counted vmcnt(8)
// (never 0 in main loop), ONE barrier per K-tile, XOR-swizzled LDS (T2,
// both-sides: pre-swizzled global source + swizzled ds_read), setprio (T5).
//
// Ordering is made compiler-proof by data dependence: the wait+barrier asm
// takes the ds_read bases (pa,pb) and staging sources (psa,psb) as "+v"
// outputs, so no LDS read or gload_lds can be hoisted above the barrier at
// any compilation level, and the chained outputs serialize step asms.
//
// Hazard proof (per step kt):
//  - reads of buf[kt&3]: every wave did s_waitcnt vmcnt(8) (own 4 loads of
//    tile kt retired -> its LDS quarter written) BEFORE the barrier; reads
//    are data-dependent on the barrier asm => safe.
//  - stage of tile kt+3 overwrites buf[(kt-1)&3], whose readers drained
//    lgkmcnt before their MFMA(kt-1), hence before reaching this barrier;
//    the stage is data-dependent on this barrier asm => safe.
// ---------------------------------------------------------------------------
extern __shared__ int8_t g_lds[];

template<int BUF, int VM, bool STG>
__device__ __forceinline__ void tile_step(
    int kt,
    const int8_t*& pa, const int8_t*& pb,
    const int8_t*& psa, const int8_t*& psb,
    int8_t* lds_st, int4v (&acc)[8][4])
{
  if constexpr (VM == 8)
    asm volatile("s_waitcnt vmcnt(8)\n\ts_barrier"
                 : "+v"(pa), "+v"(pb), "+v"(psa), "+v"(psb) :: "memory");
  else if constexpr (VM == 4)
    asm volatile("s_waitcnt vmcnt(4)\n\ts_barrier"
                 : "+v"(pa), "+v"(pb), "+v"(psa), "+v"(psb) :: "memory");
  else
    asm volatile("s_waitcnt vmcnt(0)\n\ts_barrier"
                 : "+v"(pa), "+v"(pb), "+v"(psa), "+v"(psb) :: "memory");

  int4v af[8], bf[4];
#pragma unroll
  for (int mf = 0; mf < 8; ++mf)
    af[mf] = *reinterpret_cast<const int4v*>(pa + BUF * 16384 + mf * 1024);
#pragma unroll
  for (int nf = 0; nf < 4; ++nf)
    bf[nf] = *reinterpret_cast<const int4v*>(pb + BUF * 16384 + nf * 1024);

  if constexpr (STG) {                 // stage tile kt+3 into buf (BUF+3)&3
    const int8_t* as = psa + (kt + 3) * BK;
    const int8_t* bs = psb + (kt + 3) * BK;
    int8_t* ad = lds_st + ((BUF + 3) & 3) * 16384;
    int8_t* bd = ad + 65536;
    gload_lds16(as, ad);
    gload_lds16(as + 128 * IN_F, ad + 8192);
    gload_lds16(bs, bd);
    gload_lds16(bs + 128 * IN_F, bd + 8192);
  }

  __builtin_amdgcn_s_setprio(1);
#pragma unroll
  for (int mf = 0; mf < 8; ++mf)
#pragma unroll
    for (int nf = 0; nf < 4; ++nf)
      acc[mf][nf] = __builtin_amdgcn_mfma_i32_16x16x64_i8(af[mf], bf[nf],
                                                          acc[mf][nf], 0, 0, 0);
  __builtin_amdgcn_s_setprio(0);
}

__global__ __launch_bounds__(512, 2) void gemm_kernel(
    const int8_t* __restrict__ aq, const int8_t* __restrict__ wt,
    const float* __restrict__ xs, const float* __restrict__ int8_scales,
    const float* __restrict__ bias, float* __restrict__ out)
{
  // XCD-bijective swizzle (nwg = 512, divisible by 8)
  int bid = blockIdx.x;
  bid = (bid & 7) * 64 + (bid >> 3);
  const int m0 = (bid >> 4) * BM;      // 32 m-tiles
  const int n0 = (bid & 15) * BN;      // 16 n-tiles

  const int t = threadIdx.x;
  const int l = t & 63;
  const int w = t >> 6;                // wave 0..7
  const int wm = (w >> 2) * 128;       // 2 M-wave-rows
  const int wn = (w & 3) * 64;         // 4 N-wave-cols

  // --- staging: thread t covers LDS row t>>2 slot t&3 (linear dest);
  // global source slot pre-swizzled: stored[s] = global[s ^ ((row>>1)&3)].
  const int scol = (((t & 3) ^ ((t >> 3) & 3)) << 4);
  const int8_t* psa = aq + (size_t)(m0 + (t >> 2)) * IN_F + scol;
  const int8_t* psb = wt + (size_t)(n0 + (t >> 2)) * IN_F + scol;
  int8_t* lds_st = g_lds + t * 16;

  // --- fragment-read bases: row*64 + swizzled k-slot. swz = ((l&15)>>1)&3
  // (row = wm/wn + (l&15) + {mf,nf}*16: wm,wn,16 are ==0 mod 8 rows, so the
  // swizzle term is identical for all mf/nf => one base + imm offsets).
  const int kslot = l >> 4;
  const int swz = (((l & 15) >> 1) & 3) << 4;
  const int8_t* pa = g_lds + (wm + (l & 15)) * 64 + ((kslot << 4) ^ swz);
  const int8_t* pb = g_lds + 65536 + (wn + (l & 15)) * 64 + ((kslot << 4) ^ swz);

  int4v acc[8][4];
#pragma unroll
  for (int mf = 0; mf < 8; ++mf)
#pragma unroll
    for (int nf = 0; nf < 4; ++nf)
      acc[mf][nf] = (int4v){0, 0, 0, 0};

  // --- prologue: stage tiles 0,1,2 (issue order defines vmcnt accounting)
#pragma unroll
  for (int pt = 0; pt < 3; ++pt) {
    const int8_t* as = psa + pt * BK;
    const int8_t* bs = psb + pt * BK;
    int8_t* ad = lds_st + pt * 16384;
    int8_t* bd = ad + 65536;
    gload_lds16(as, ad);
    gload_lds16(as + 128 * IN_F, ad + 8192);
    gload_lds16(bs, bd);
    gload_lds16(bs + 128 * IN_F, bd + 8192);
  }

  // --- main loop: steps 0..59 stage tiles 3..62
#pragma unroll 1
  for (int kt = 0; kt < 60; kt += 4) {
    tile_step<0, 8, true>(kt + 0, pa, pb, psa, psb, lds_st, acc);
    tile_step<1, 8, true>(kt + 1, pa, pb, psa, psb, lds_st, acc);
    tile_step<2, 8, true>(kt + 2, pa, pb, psa, psb, lds_st, acc);
    tile_step<3, 8, true>(kt + 3, pa, pb, psa, psb, lds_st, acc);
  }
  // --- tail: step 60 stages tile 63; 61/62/63 drain with counted waits
  tile_step<0, 8, true >(60, pa, pb, psa, psb, lds_st, acc);
  tile_step<1, 8, false>(61, pa, pb, psa, psb, lds_st, acc);
  tile_step<2, 4, false>(62, pa, pb, psa, psb, lds_st, acc);
  tile_step<3, 0, false>(63, pa, pb, psa, psb, lds_st, acc);

  // --- epilogue: C/D layout col = l&15, row = (l>>4)*4 + r
  const int col_l = l & 15;
  const int row_l = (l >> 4) * 4;
  float xsv[8][4];
#pragma unroll
  for (int mf = 0; mf < 8; ++mf)
#pragma unroll
    for (int r = 0; r < 4; ++r)
      xsv[mf][r] = xs[m0 + wm + mf * 16 + row_l + r];

#pragma unroll
  for (int nf = 0; nf < 4; ++nf) {
    const int col = n0 + wn + nf * 16 + col_l;
    const float is = int8_scales[col];
    const float bv = bias[col];
#pragma unroll
    for (int mf = 0; mf < 8; ++mf) {
      const int rowb = m0 + wm + mf * 16 + row_l;
#pragma unroll
      for (int r = 0; r < 4; ++r)
        out[(size_t)(rowb + r) * OUT_F + col] =
            (float)acc[mf][nf][r] * (xsv[mf][r] * is) + bv;
    }
  }
}

// ---------------------------------------------------------------------------
extern "C" void kernel_launch(void* const* d_in, const int* in_sizes, int n_in,
                              void* d_out, int out_size, void* d_ws, size_t ws_size,
                              hipStream_t stream) {
  const float* x           = (const float*)d_in[0];
  const int*   qweight     = (const int*)d_in[1];
  const int*   qzeros      = (const int*)d_in[2];
  const float* scales      = (const float*)d_in[3];
  const float* int8_scales = (const float*)d_in[4];
  const float* bias        = (const float*)d_in[5];
  float* out = (float*)d_out;

  // workspace: A_q [8192][4096] i8 | WT [4096][4096] i8 | xs [8192] f32
  int8_t* aq = (int8_t*)d_ws;
  int8_t* wt = aq + (size_t)NTOK * IN_F;
  float*  xs = (float*)(wt + (size_t)OUT_F * IN_F);

  // Unconditional (no static guards per harness rules); host-side, idempotent,
  // not a stream op -> graph-capture safe.
  (void)hipFuncSetAttribute((const void*)gemm_kernel,
                            hipFuncAttributeMaxDynamicSharedMemorySize, 131072);

  act_quant_kernel<<<NTOK, 256, 0, stream>>>(x, aq, xs);
  wdq_kernel<<<dim3(IN_F / 128, OUT_F / 64), 256, 0, stream>>>(qweight, qzeros, scales, wt);
  gemm_kernel<<<(NTOK / BM) * (OUT_F / BN), 512, 131072, stream>>>(aq, wt, xs, int8_scales, bias, out);
}

// Round 8
// 366.317 us; speedup vs baseline: 1.2315x; 1.2315x over previous
//
#include <hip/hip_runtime.h>
#include <stdint.h>

#define IN_F 4096
#define OUT_F 4096
#define NTOK 8192   // 4 * 2048
#define BM 256
#define BN 256
#define BK 128      // i8: 128 B rows
#define NKT (IN_F / BK)   // 32 K-tiles

typedef int int4v __attribute__((ext_vector_type(4)));

typedef const __attribute__((address_space(1))) void* gas1_t;
typedef __attribute__((address_space(3))) void* gas3_t;

__device__ __forceinline__ void gload_lds16(const int8_t* g, int8_t* l) {
  __builtin_amdgcn_global_load_lds((gas1_t)(const void*)g, (gas3_t)(void*)l, 16, 0, 0);
}

// ---------------------------------------------------------------------------
// Kernel 1: per-token activation quantization (passed r4).
// ---------------------------------------------------------------------------
__global__ __launch_bounds__(256) void act_quant_kernel(
    const float* __restrict__ x, int8_t* __restrict__ xq, float* __restrict__ xs)
{
  const int row = blockIdx.x;
  const int t = threadIdx.x;
  const float4* xr = reinterpret_cast<const float4*>(x + (size_t)row * IN_F);
  float4 v[4];
  float amax = 0.f;
#pragma unroll
  for (int i = 0; i < 4; ++i) {
    v[i] = xr[t + i * 256];
    amax = fmaxf(amax, fmaxf(fmaxf(fabsf(v[i].x), fabsf(v[i].y)),
                             fmaxf(fabsf(v[i].z), fabsf(v[i].w))));
  }
#pragma unroll
  for (int off = 32; off; off >>= 1)
    amax = fmaxf(amax, __shfl_xor(amax, off));
  __shared__ float red[4];
  if ((t & 63) == 0) red[t >> 6] = amax;
  __syncthreads();
  amax = fmaxf(fmaxf(red[0], red[1]), fmaxf(red[2], red[3]));
  const float s = amax / 127.0f;   // IEEE div to match jnp
  if (t == 0) xs[row] = s;

  uint32_t* xqw = reinterpret_cast<uint32_t*>(xq + (size_t)row * IN_F);
#pragma unroll
  for (int i = 0; i < 4; ++i) {
    int q0 = (int)rintf(v[i].x / s);
    int q1 = (int)rintf(v[i].y / s);
    int q2 = (int)rintf(v[i].z / s);
    int q3 = (int)rintf(v[i].w / s);
    q0 = max(-128, min(127, q0));
    q1 = max(-128, min(127, q1));
    q2 = max(-128, min(127, q2));
    q3 = max(-128, min(127, q3));
    xqw[t + i * 256] = (q0 & 255) | ((q1 & 255) << 8) | ((q2 & 255) << 16) | (q3 << 24);
  }
}

// ---------------------------------------------------------------------------
// Kernel 2: weight dequant + transpose to WT[N][K] int8 (passed r2/r4).
// ---------------------------------------------------------------------------
__global__ __launch_bounds__(256) void wdq_kernel(
    const int* __restrict__ qweight, const int* __restrict__ qzeros,
    const float* __restrict__ scales, int8_t* __restrict__ wt)
{
  __shared__ int8_t tile[64 * 144];
  const int t = threadIdx.x;
  const int g = blockIdx.x;
  const int o0 = blockIdx.y * 64;
  const int i0 = g * 16;
  const int ol = t & 63;
  const int o = o0 + ol;

  const int zw = qzeros[g * (OUT_F / 8) + (o >> 3)];
  const int znib = (zw >> ((o & 7) * 4)) & 15;
  const float sc = scales[g * OUT_F + o];

#pragma unroll
  for (int j = 0; j < 4; ++j) {
    const int il = j * 4 + (t >> 6);
    const int w = qweight[(size_t)(i0 + il) * OUT_F + o];
    uint64_t packed = 0;
#pragma unroll
    for (int nb = 0; nb < 8; ++nb) {
      const int wnib = (w >> (nb * 4)) & 15;
      const int8_t diff = (int8_t)(((wnib - znib) & 15) << 4);
      float val = rintf(sc * (float)diff);
      val = fminf(127.f, fmaxf(-128.f, val));
      packed |= (uint64_t)(uint8_t)(int8_t)(int)val << (8 * nb);
    }
    *reinterpret_cast<uint64_t*>(&tile[ol * 144 + il * 8]) = packed;
  }
  __syncthreads();
  const int orow = t >> 2;
  const int kb = (t & 3) * 32;
  int4v w0 = *reinterpret_cast<int4v*>(&tile[orow * 144 + kb]);
  int4v w1 = *reinterpret_cast<int4v*>(&tile[orow * 144 + kb + 16]);
  int8_t* dst = wt + (size_t)(o0 + orow) * IN_F + g * 128 + kb;
  *reinterpret_cast<int4v*>(dst) = w0;
  *reinterpret_cast<int4v*>(dst + 16) = w1;
}

// ---------------------------------------------------------------------------
// Kernel 3: 8-phase int8 GEMM, race-fixed publication protocol.
// 256x256, BK=128, 8 waves (2Mx4N), NKT=32 groups.
// LDS: A dbuf slot*32768 in [0,64K); B dbuf at +65536.
// Swizzle: LDS[row][s16] = global[row][s16 ^ (row&7)].
//
// Stage stream (2 gloads per half-stage, 8 per tile):
//   group kt: q0: tile kt+1 A rows[128,256)   q1: tile kt+1 B rows[0,128)
//             q2: tile kt+1 B rows[128,256)   q3: tile kt+2 A rows[0,128)
//   (tile kt+1 A rows[0,128) staged by group kt-1's q3)
// Publication: q3 issues its stage, then s_waitcnt vmcnt(2) -- drains ALL 8
// loads of tile kt+1, leaves tile kt+2's 2 -- then s_barrier publishes.
// Group kt+1's ds_reads follow that barrier. RAW safe.
// WAR: q3's overwrite of current-slot rows[0,128) is safe because wave X
// issues it only after q2's END barrier, which every wave Y passes only
// after its q2 LGKM0 (reads returned). Tail: group 30 q3 no stage ->
// vmcnt(0) drains tile 31's 8; group 31 no stages.
// ---------------------------------------------------------------------------
extern __shared__ int8_t g_lds[];

template<int SLOT, int MFH>
__device__ __forceinline__ void load_a(const int8_t* pa0, const int8_t* pa1,
                                       int4v (&af)[4][2]) {
#pragma unroll
  for (int mf = 0; mf < 4; ++mf) {
    af[mf][0] = *reinterpret_cast<const int4v*>(pa0 + SLOT * 32768 + (MFH * 4 + mf) * 2048);
    af[mf][1] = *reinterpret_cast<const int4v*>(pa1 + SLOT * 32768 + (MFH * 4 + mf) * 2048);
  }
}
template<int SLOT, int NFH>
__device__ __forceinline__ void load_b(const int8_t* pb0, const int8_t* pb1,
                                       int4v (&bf)[2][2]) {
#pragma unroll
  for (int nf = 0; nf < 2; ++nf) {
    bf[nf][0] = *reinterpret_cast<const int4v*>(pb0 + SLOT * 32768 + (NFH * 2 + nf) * 2048);
    bf[nf][1] = *reinterpret_cast<const int4v*>(pb1 + SLOT * 32768 + (NFH * 2 + nf) * 2048);
  }
}
template<int MFH, int NFH>
__device__ __forceinline__ void mfma_quad(const int4v (&af)[4][2],
                                          const int4v (&bf)[2][2],
                                          int4v (&acc)[8][4]) {
  __builtin_amdgcn_sched_barrier(0);   // rule #18: pin MFMA below LGKM0
  __builtin_amdgcn_s_setprio(1);
#pragma unroll
  for (int mf = 0; mf < 4; ++mf)
#pragma unroll
    for (int nf = 0; nf < 2; ++nf)
#pragma unroll
      for (int kk = 0; kk < 2; ++kk)
        acc[MFH * 4 + mf][NFH * 2 + nf] = __builtin_amdgcn_mfma_i32_16x16x64_i8(
            af[mf][kk], bf[nf][kk], acc[MFH * 4 + mf][NFH * 2 + nf], 0, 0, 0);
  __builtin_amdgcn_s_setprio(0);
  __builtin_amdgcn_sched_barrier(0);
}

#define BAR()    asm volatile("s_barrier" ::: "memory")
#define LGKM0()  asm volatile("s_waitcnt lgkmcnt(0)" ::: "memory")

template<int SLOT, bool STGN, bool STGQ3, int VM>
__device__ __forceinline__ void ktile_group(
    int kt, const int8_t* psa, const int8_t* psb, int8_t* lds_st,
    const int8_t* pa0, const int8_t* pa1, const int8_t* pb0, const int8_t* pb1,
    int4v (&acc)[8][4])
{
  int4v af[4][2], b0f[2][2], b1f[2][2];
  const int8_t* sa1 = psa + (size_t)(kt + 1) * BK;
  const int8_t* sb1 = psb + (size_t)(kt + 1) * BK;
  int8_t* dn_a = lds_st + (SLOT ^ 1) * 32768;   // next-tile dest (A); B at +65536
  int8_t* dn_b = dn_a + 65536;

  // q0: ds A(MFH0)+B(NFH0); stage next-tile A rows[128,256)
  load_a<SLOT, 0>(pa0, pa1, af);
  load_b<SLOT, 0>(pb0, pb1, b0f);
  if constexpr (STGN) {
    gload_lds16(sa1 + (size_t)128 * IN_F, dn_a + 16384);
    gload_lds16(sa1 + (size_t)192 * IN_F, dn_a + 24576);
  }
  BAR(); LGKM0();
  mfma_quad<0, 0>(af, b0f, acc);
  BAR();

  // q1: ds B(NFH1); stage next-tile B rows[0,128)
  load_b<SLOT, 1>(pb0, pb1, b1f);
  if constexpr (STGN) {
    gload_lds16(sb1, dn_b);
    gload_lds16(sb1 + (size_t)64 * IN_F, dn_b + 8192);
  }
  BAR(); LGKM0();
  mfma_quad<0, 1>(af, b1f, acc);
  BAR();

  // q2: ds A(MFH1); stage next-tile B rows[128,256)
  load_a<SLOT, 1>(pa0, pa1, af);
  if constexpr (STGN) {
    gload_lds16(sb1 + (size_t)128 * IN_F, dn_b + 16384);
    gload_lds16(sb1 + (size_t)192 * IN_F, dn_b + 24576);
  }
  BAR(); LGKM0();
  mfma_quad<1, 0>(af, b0f, acc);
  BAR();

  // q3: stage tile kt+2 A rows[0,128) into CURRENT slot (readers drained at
  // q0/q2 per WAR proof); counted vmcnt; barrier PUBLISHES tile kt+1.
  if constexpr (STGQ3) {
    const int8_t* sa2 = psa + (size_t)(kt + 2) * BK;
    int8_t* dc_a = lds_st + SLOT * 32768;
    gload_lds16(sa2, dc_a);
    gload_lds16(sa2 + (size_t)64 * IN_F, dc_a + 8192);
  }
  if constexpr (VM == 2) asm volatile("s_waitcnt vmcnt(2)" ::: "memory");
  else                   asm volatile("s_waitcnt vmcnt(0)" ::: "memory");
  BAR(); LGKM0();
  mfma_quad<1, 1>(af, b1f, acc);
  BAR();
}

__global__ __launch_bounds__(512, 1) void gemm_kernel(
    const int8_t* __restrict__ aq, const int8_t* __restrict__ wt,
    const float* __restrict__ xs, const float* __restrict__ int8_scales,
    const float* __restrict__ bias, float* __restrict__ out)
{
  // XCD-bijective swizzle (nwg = 512)
  int bid = blockIdx.x;
  bid = (bid & 7) * 64 + (bid >> 3);
  const int m0 = (bid >> 4) * BM;
  const int n0 = (bid & 15) * BN;

  const int t = threadIdx.x;
  const int l = t & 63;
  const int w = t >> 6;
  const int wm = (w >> 2) * 128;
  const int wn = (w & 3) * 64;

  // staging: thread t -> LDS row t>>3, slot t&7 (linear dest); source slot
  // pre-swizzled: stored[row][s] = global[row][s ^ (row&7)]
  const size_t s_off = (size_t)(t >> 3) * IN_F + (size_t)(((t & 7) ^ ((t >> 3) & 7)) << 4);
  const int8_t* psa = aq + (size_t)m0 * IN_F + s_off;
  const int8_t* psb = wt + (size_t)n0 * IN_F + s_off;
  int8_t* lds_st = g_lds + t * 16;

  // fragment-read bases: row*128 + ((kk*4 + l>>4) ^ (l&7))*16; row&7 == l&7
  // for all mf/nf (wm, wn, 16-row steps all ==0 mod 8)
  const int lr = l & 15;
  const int ks = l >> 4;
  const int sw = l & 7;
  const int8_t* pa0 = g_lds + (wm + lr) * 128 + (((0 * 4 + ks) ^ sw) << 4);
  const int8_t* pa1 = g_lds + (wm + lr) * 128 + (((1 * 4 + ks) ^ sw) << 4);
  const int8_t* pb0 = g_lds + 65536 + (wn + lr) * 128 + (((0 * 4 + ks) ^ sw) << 4);
  const int8_t* pb1 = g_lds + 65536 + (wn + lr) * 128 + (((1 * 4 + ks) ^ sw) << 4);

  int4v acc[8][4];
#pragma unroll
  for (int mf = 0; mf < 8; ++mf)
#pragma unroll
    for (int nf = 0; nf < 4; ++nf)
      acc[mf][nf] = (int4v){0, 0, 0, 0};

  // prologue: tile 0 fully (8 loads, slot 0) + tile 1 A rows[0,128) (2, slot 1);
  // vmcnt(2) drains tile 0; barrier publishes it.
#pragma unroll
  for (int r = 0; r < 4; ++r)
    gload_lds16(psa + (size_t)(r * 64) * IN_F, lds_st + r * 8192);
#pragma unroll
  for (int r = 0; r < 4; ++r)
    gload_lds16(psb + (size_t)(r * 64) * IN_F, lds_st + 65536 + r * 8192);
  gload_lds16(psa + BK, lds_st + 32768);
  gload_lds16(psa + BK + (size_t)64 * IN_F, lds_st + 32768 + 8192);
  asm volatile("s_waitcnt vmcnt(2)" ::: "memory");
  BAR();

  // main: groups 0..29 uniform; 30 (stages tile 31 only, vmcnt 0); 31 (none)
#pragma unroll 1
  for (int kt = 0; kt < 30; kt += 2) {
    ktile_group<0, true, true, 2>(kt,     psa, psb, lds_st, pa0, pa1, pb0, pb1, acc);
    ktile_group<1, true, true, 2>(kt + 1, psa, psb, lds_st, pa0, pa1, pb0, pb1, acc);
  }
  ktile_group<0, true,  false, 0>(30, psa, psb, lds_st, pa0, pa1, pb0, pb1, acc);
  ktile_group<1, false, false, 0>(31, psa, psb, lds_st, pa0, pa1, pb0, pb1, acc);

  // epilogue: C/D layout col = l&15, row = (l>>4)*4 + r (verified r2/r4)
  const int col_l = l & 15;
  const int row_l = (l >> 4) * 4;
  float xsv[8][4];
#pragma unroll
  for (int mf = 0; mf < 8; ++mf)
#pragma unroll
    for (int r = 0; r < 4; ++r)
      xsv[mf][r] = xs[m0 + wm + mf * 16 + row_l + r];

#pragma unroll
  for (int nf = 0; nf < 4; ++nf) {
    const int col = n0 + wn + nf * 16 + col_l;
    const float is = int8_scales[col];
    const float bv = bias[col];
#pragma unroll
    for (int mf = 0; mf < 8; ++mf) {
      const int rowb = m0 + wm + mf * 16 + row_l;
#pragma unroll
      for (int r = 0; r < 4; ++r)
        out[(size_t)(rowb + r) * OUT_F + col] =
            (float)acc[mf][nf][r] * (xsv[mf][r] * is) + bv;
    }
  }
}

// ---------------------------------------------------------------------------
extern "C" void kernel_launch(void* const* d_in, const int* in_sizes, int n_in,
                              void* d_out, int out_size, void* d_ws, size_t ws_size,
                              hipStream_t stream) {
  const float* x           = (const float*)d_in[0];
  const int*   qweight     = (const int*)d_in[1];
  const int*   qzeros      = (const int*)d_in[2];
  const float* scales      = (const float*)d_in[3];
  const float* int8_scales = (const float*)d_in[4];
  const float* bias        = (const float*)d_in[5];
  float* out = (float*)d_out;

  // workspace: A_q [8192][4096] i8 | WT [4096][4096] i8 | xs [8192] f32
  int8_t* aq = (int8_t*)d_ws;
  int8_t* wt = aq + (size_t)NTOK * IN_F;
  float*  xs = (float*)(wt + (size_t)OUT_F * IN_F);

  (void)hipFuncSetAttribute((const void*)gemm_kernel,
                            hipFuncAttributeMaxDynamicSharedMemorySize, 131072);

  act_quant_kernel<<<NTOK, 256, 0, stream>>>(x, aq, xs);
  wdq_kernel<<<dim3(IN_F / 128, OUT_F / 64), 256, 0, stream>>>(qweight, qzeros, scales, wt);
  gemm_kernel<<<(NTOK / BM) * (OUT_F / BN), 512, 131072, stream>>>(aq, wt, xs, int8_scales, bias, out);
}